// Round 1
// baseline (2360.665 us; speedup 1.0000x reference)
//
#include <hip/hip_runtime.h>

// Jacobi heat iteration: x <- 0.25*(up+down+left+right) + COF*layout,
// reflect boundaries (jnp.pad mode="reflect": edge mirrors to index 1 / NX-2).
// 50 iterations, ping-pong between d_ws and d_out.

#define NX 1024
#define BATCH 16
#define NITER 50

// COF computed in double then rounded to f32 (matches Python float -> f32 promotion)
__device__ __constant__ float kCOF = (float)(0.25 * (0.1 / 1023.0) * (0.1 / 1023.0));

__global__ __launch_bounds__(256) void jacobi_step(const float* __restrict__ x,
                                                   const float* __restrict__ layout,
                                                   float* __restrict__ out) {
    // One thread = 4 contiguous columns (float4). Total threads = BATCH*NX*NX/4.
    int tid = blockIdx.x * blockDim.x + threadIdx.x;
    int j4   = tid & (NX / 4 - 1);     // 0..255 (float4 group within row)
    int rest = tid >> 8;               // global row index
    int i    = rest & (NX - 1);        // row within image
    int b    = rest >> 10;             // batch

    long base = (long)b * NX * NX;
    const float* xb = x + base;
    int j0 = j4 * 4;

    int up = (i == 0)      ? 1      : i - 1;
    int dn = (i == NX - 1) ? NX - 2 : i + 1;

    const float4 cu = *(const float4*)(xb + (long)up * NX + j0);
    const float4 cd = *(const float4*)(xb + (long)dn * NX + j0);
    const float4 cc = *(const float4*)(xb + (long)i  * NX + j0);

    // reflect at row edges: left of j=0 is x[1] (= cc.y); right of j=NX-1 is x[NX-2] (= cc.z)
    float left  = (j0 == 0)       ? cc.y : xb[(long)i * NX + j0 - 1];
    float right = (j0 + 4 == NX)  ? cc.z : xb[(long)i * NX + j0 + 4];

    const float4 f4 = *(const float4*)(layout + base + (long)i * NX + j0);

    float4 o;
    o.x = 0.25f * (cu.x + cd.x + left  + cc.y) + kCOF * f4.x;
    o.y = 0.25f * (cu.y + cd.y + cc.x  + cc.z) + kCOF * f4.y;
    o.z = 0.25f * (cu.z + cd.z + cc.y  + cc.w) + kCOF * f4.z;
    o.w = 0.25f * (cu.w + cd.w + cc.z  + right) + kCOF * f4.w;

    *(float4*)(out + base + (long)i * NX + j0) = o;
}

extern "C" void kernel_launch(void* const* d_in, const int* in_sizes, int n_in,
                              void* d_out, int out_size, void* d_ws, size_t ws_size,
                              hipStream_t stream) {
    const float* layout = (const float*)d_in[0];
    const float* heat   = (const float*)d_in[1];
    float* out = (float*)d_out;
    float* ws  = (float*)d_ws;

    const int total_threads = BATCH * NX * (NX / 4);   // 4,194,304
    const int block = 256;
    const int grid  = total_threads / block;           // 16,384

    // it=0 writes ws, it=1 writes out, ... it=49 (odd) writes out. Final in d_out.
    const float* src = heat;
    for (int it = 0; it < NITER; ++it) {
        float* dst = (it & 1) ? out : ws;
        jacobi_step<<<grid, block, 0, stream>>>(src, layout, dst);
        src = dst;
    }
}

// Round 2
// 864.305 us; speedup vs baseline: 2.7313x; 2.7313x over previous
//
#include <hip/hip_runtime.h>

// Temporally-blocked Jacobi: 5 launches x 10 fused steps in LDS.
// Tile: 44x44 output, 64x64 staged (halo=10). Reflect handled by loading
// reflect-mapped halos (symmetric extension commutes with the stencil).
// Each thread owns a fixed 4x4 patch (16 col-groups x 16 row-chunks = 256 thr),
// computes it every step; garbage rings propagate 1 cell/step and never reach
// the central 44x44. f = COF*layout kept in registers across all 10 steps.

#define NX 1024
#define BATCH 16
#define TSTEPS 10
#define OUT 44
#define SZ 64            // OUT + 2*TSTEPS
#define PITCH 72         // 4 pad + 64 data + 4 pad floats per LDS row
#define LROWS 66         // 64 data rows + 2 pad rows

__device__ __forceinline__ int reflect_idx(int i) {
    i = (i < 0) ? -i : i;
    return (i > NX - 1) ? 2 * (NX - 1) - i : i;
}

__global__ __launch_bounds__(256) void jacobi_fused(const float* __restrict__ src,
                                                    const float* __restrict__ layout,
                                                    float* __restrict__ dst) {
    __shared__ float buf[2][LROWS * PITCH];

    const float COF = (float)(0.25 * (0.1 / 1023.0) * (0.1 / 1023.0));

    const int tid = threadIdx.x;
    const int g = tid & 15;          // col group (data cols 4g..4g+3)
    const int c = tid >> 4;          // row chunk (buffer rows 1+4c..4+4c)
    const int gr0 = blockIdx.y * OUT - TSTEPS;   // global row of buffer row 0
    const int gc0 = blockIdx.x * OUT - TSTEPS;   // global col of data col 0
    const int base = blockIdx.z * NX * NX;

    // ---- stage x tile (64x64) into buf[0], reflect-mapped, coalesced ----
#pragma unroll
    for (int k = 0; k < 16; ++k) {
        int idx = tid + 256 * k;
        int r = idx >> 6, q = idx & 63;
        int grr = reflect_idx(gr0 + r);
        int gcc = reflect_idx(gc0 + q);
        buf[0][r * PITCH + 4 + q] = src[base + grr * NX + gcc];
    }

    // ---- f = COF*layout at this thread's 16 fixed points, in registers ----
    const int R0 = 1 + 4 * c;        // first computed buffer row (1..61)
    const int C0 = 4 + 4 * g;        // first LDS col of patch
    float f[4][4];
#pragma unroll
    for (int i = 0; i < 4; ++i) {
        int grr = reflect_idx(gr0 + R0 + i);
#pragma unroll
        for (int k = 0; k < 4; ++k) {
            int gcc = reflect_idx(gc0 + 4 * g + k);
            f[i][k] = COF * layout[base + grr * NX + gcc];
        }
    }
    __syncthreads();

    // ---- 10 fused Jacobi steps, ping-pong LDS ----
#pragma unroll 2
    for (int s = 0; s < TSTEPS; ++s) {
        const float* sb = buf[s & 1];
        float* db = buf[(s & 1) ^ 1];

        float4 rv[6];                 // rows R0-1 .. R0+4, cols C0..C0+3
#pragma unroll
        for (int j = 0; j < 6; ++j)
            rv[j] = *(const float4*)&sb[(R0 - 1 + j) * PITCH + C0];

        float lf[4], rt[4];
#pragma unroll
        for (int i = 0; i < 4; ++i) {
            lf[i] = sb[(R0 + i) * PITCH + C0 - 1];
            rt[i] = sb[(R0 + i) * PITCH + C0 + 4];
        }

#pragma unroll
        for (int i = 0; i < 4; ++i) {
            float4 o;
            o.x = 0.25f * (rv[i].x + rv[i + 2].x + lf[i]       + rv[i + 1].y) + f[i][0];
            o.y = 0.25f * (rv[i].y + rv[i + 2].y + rv[i + 1].x + rv[i + 1].z) + f[i][1];
            o.z = 0.25f * (rv[i].z + rv[i + 2].z + rv[i + 1].y + rv[i + 1].w) + f[i][2];
            o.w = 0.25f * (rv[i].w + rv[i + 2].w + rv[i + 1].z + rt[i])       + f[i][3];
            *(float4*)&db[(R0 + i) * PITCH + C0] = o;
        }
        __syncthreads();
    }

    // ---- store central 44x44 (data rows/cols 10..53) from buf[0] ----
#pragma unroll
    for (int i = 0; i < 4; ++i) {
        int br = R0 + i;                       // == data row index
        if (br < TSTEPS || br > SZ - 1 - TSTEPS) continue;
        int grr = gr0 + br;
        if (grr >= NX) continue;
#pragma unroll
        for (int k = 0; k < 4; ++k) {
            int dcol = 4 * g + k;
            if (dcol < TSTEPS || dcol > SZ - 1 - TSTEPS) continue;
            int gcc = gc0 + dcol;
            if (gcc >= NX) continue;
            dst[base + grr * NX + gcc] = buf[0][br * PITCH + C0 + k];
        }
    }
}

extern "C" void kernel_launch(void* const* d_in, const int* in_sizes, int n_in,
                              void* d_out, int out_size, void* d_ws, size_t ws_size,
                              hipStream_t stream) {
    const float* layout = (const float*)d_in[0];
    const float* heat   = (const float*)d_in[1];
    float* out = (float*)d_out;
    float* ws  = (float*)d_ws;

    dim3 grid((NX + OUT - 1) / OUT, (NX + OUT - 1) / OUT, BATCH);  // 24 x 24 x 16
    dim3 block(256);

    // 5 launches x 10 steps = 50. Chain: heat->out->ws->out->ws->out.
    jacobi_fused<<<grid, block, 0, stream>>>(heat, layout, out);
    jacobi_fused<<<grid, block, 0, stream>>>(out,  layout, ws);
    jacobi_fused<<<grid, block, 0, stream>>>(ws,   layout, out);
    jacobi_fused<<<grid, block, 0, stream>>>(out,  layout, ws);
    jacobi_fused<<<grid, block, 0, stream>>>(ws,   layout, out);
}

// Round 3
// 539.431 us; speedup vs baseline: 4.3762x; 1.6023x over previous
//
#include <hip/hip_runtime.h>

// Temporally-blocked Jacobi, register-resident: 5 launches x 10 fused steps.
// Tile 44x44 output, 64x64 staged (halo=10). Each thread owns a 4x4 patch in
// registers across all 10 steps. Per step, only the 2 boundary rows of each
// 4-row chunk go through LDS (b128, conflict-free); left/right neighbors come
// from DPP row shifts (VALU, no LDS pipe). f=COF*layout lives in registers.
// Garbage/stale rings propagate 1 cell/step and never reach the central 44x44.

#define NX 1024
#define BATCH 16
#define TSTEPS 10
#define OUT 44
#define HI 53            // last valid data row/col = SZ-1-TSTEPS
#define PITCH 64
#define LROWS 66

__device__ __forceinline__ int reflect_idx(int i) {
    i = (i < 0) ? -i : i;
    return (i > NX - 1) ? 2 * (NX - 1) - i : i;
}

// lane g receives lane g-1's value (within each 16-lane DPP row); row edges keep own (garbage-allowed)
__device__ __forceinline__ float dpp_shr1(float x) {
    int v = __float_as_int(x);
    return __int_as_float(__builtin_amdgcn_update_dpp(v, v, 0x111, 0xF, 0xF, false));
}
// lane g receives lane g+1's value
__device__ __forceinline__ float dpp_shl1(float x) {
    int v = __float_as_int(x);
    return __int_as_float(__builtin_amdgcn_update_dpp(v, v, 0x101, 0xF, 0xF, false));
}

__global__ __launch_bounds__(256, 4) void jacobi_fused(const float* __restrict__ src,
                                                       const float* __restrict__ layout,
                                                       float* __restrict__ dst) {
    __shared__ float buf[2][LROWS * PITCH];

    const float COF = (float)(0.25 * (0.1 / 1023.0) * (0.1 / 1023.0));

    const int tid = threadIdx.x;
    const int g = tid & 15;                      // col group: data cols 4g..4g+3
    const int c = tid >> 4;                      // row chunk: buffer rows 1+4c..4+4c
    const int gr0 = blockIdx.y * OUT - TSTEPS;   // global row of buffer row 0
    const int gc0 = blockIdx.x * OUT - TSTEPS;   // global col of data col 0
    const int base = blockIdx.z * NX * NX;

    // ---- stage x tile (64x64) into buf[0], reflect-mapped ----
#pragma unroll
    for (int k = 0; k < 16; ++k) {
        int idx = tid + 256 * k;
        int r = idx >> 6, q = idx & 63;
        buf[0][r * PITCH + q] = src[base + reflect_idx(gr0 + r) * NX + reflect_idx(gc0 + q)];
    }

    const int R0 = 1 + 4 * c;
    const int C0 = 4 * g;

    // ---- f = COF*layout at fixed points, registers ----
    float f[4][4];
#pragma unroll
    for (int i = 0; i < 4; ++i) {
        int grr = reflect_idx(gr0 + R0 + i);
#pragma unroll
        for (int k = 0; k < 4; ++k)
            f[i][k] = COF * layout[base + grr * NX + reflect_idx(gc0 + C0 + k)];
    }
    __syncthreads();

    // ---- load center 4 rows into registers ----
    float4 cur[4];
#pragma unroll
    for (int i = 0; i < 4; ++i)
        cur[i] = *(const float4*)&buf[0][(R0 + i) * PITCH + C0];

    // ---- 10 fused steps; only boundary rows touch LDS ----
#pragma unroll
    for (int s = 0; s < TSTEPS; ++s) {
        if (s > 0) {
            float* bb = buf[s & 1];
            *(float4*)&bb[R0 * PITCH + C0]       = cur[0];
            *(float4*)&bb[(R0 + 3) * PITCH + C0] = cur[3];
            __syncthreads();
        }
        const float* rb = (s == 0) ? buf[0] : buf[s & 1];
        float4 top = *(const float4*)&rb[(R0 - 1) * PITCH + C0];
        float4 bot = *(const float4*)&rb[(R0 + 4) * PITCH + C0];

        float lf[4], rt[4];
#pragma unroll
        for (int i = 0; i < 4; ++i) {
            lf[i] = dpp_shr1(cur[i].w);
            rt[i] = dpp_shl1(cur[i].x);
        }

        float4 nxt[4];
#pragma unroll
        for (int i = 0; i < 4; ++i) {
            float4 up = (i == 0) ? top : cur[i - 1];
            float4 dn = (i == 3) ? bot : cur[i + 1];
            nxt[i].x = 0.25f * (up.x + dn.x + lf[i]     + cur[i].y) + f[i][0];
            nxt[i].y = 0.25f * (up.y + dn.y + cur[i].x  + cur[i].z) + f[i][1];
            nxt[i].z = 0.25f * (up.z + dn.z + cur[i].y  + cur[i].w) + f[i][2];
            nxt[i].w = 0.25f * (up.w + dn.w + cur[i].z  + rt[i])    + f[i][3];
        }
#pragma unroll
        for (int i = 0; i < 4; ++i) cur[i] = nxt[i];
    }

    // ---- store central 44x44 straight from registers ----
#pragma unroll
    for (int i = 0; i < 4; ++i) {
        int br = R0 + i;
        bool rowok = (br >= TSTEPS) && (br <= HI) && (gr0 + br < NX);
        float v[4] = {cur[i].x, cur[i].y, cur[i].z, cur[i].w};
#pragma unroll
        for (int k = 0; k < 4; ++k) {
            int dcol = C0 + k;
            if (rowok && dcol >= TSTEPS && dcol <= HI && (gc0 + dcol) < NX)
                dst[base + (gr0 + br) * NX + (gc0 + dcol)] = v[k];
        }
    }
}

extern "C" void kernel_launch(void* const* d_in, const int* in_sizes, int n_in,
                              void* d_out, int out_size, void* d_ws, size_t ws_size,
                              hipStream_t stream) {
    const float* layout = (const float*)d_in[0];
    const float* heat   = (const float*)d_in[1];
    float* out = (float*)d_out;
    float* ws  = (float*)d_ws;

    dim3 grid((NX + OUT - 1) / OUT, (NX + OUT - 1) / OUT, BATCH);  // 24 x 24 x 16
    dim3 block(256);

    jacobi_fused<<<grid, block, 0, stream>>>(heat, layout, out);
    jacobi_fused<<<grid, block, 0, stream>>>(out,  layout, ws);
    jacobi_fused<<<grid, block, 0, stream>>>(ws,   layout, out);
    jacobi_fused<<<grid, block, 0, stream>>>(out,  layout, ws);
    jacobi_fused<<<grid, block, 0, stream>>>(ws,   layout, out);
}

// Round 4
// 461.869 us; speedup vs baseline: 5.1111x; 1.1679x over previous
//
#include <hip/hip_runtime.h>

// Temporally-blocked Jacobi, register-resident + packed-fp32: 5 x 10 steps.
// Tile 44x44 out, 64x64 staged (halo=10). Thread owns a 4x4 patch held as
// strided pairs E=(c0,c2), O=(c1,c3) so v_pk_add_f32 / v_pk_fma_f32 cover
// vertical + combine + fma with aligned operands; horizontal shifted operands
// need only 1 DPP + 1 mov each. LDS (boundary-row exchange) uses the same
// permuted layout (staging writes are bit-swapped), so no per-step repacking.
// Interior blocks (84%) stage via coalesced float2 loads with no reflect math.

#define NX 1024
#define BATCH 16
#define TSTEPS 10
#define OUT 44
#define HI 53            // last valid data row/col
#define PITCH 64
#define LROWS 66

typedef float v2f __attribute__((ext_vector_type(2)));

__device__ __forceinline__ int reflect_idx(int i) {
    i = (i < 0) ? -i : i;
    return (i > NX - 1) ? 2 * (NX - 1) - i : i;
}

// lane g gets lane g-1's value within each 16-lane DPP row (edges keep own: garbage-allowed)
__device__ __forceinline__ float dpp_shr1(float x) {
    int v = __float_as_int(x);
    return __int_as_float(__builtin_amdgcn_update_dpp(v, v, 0x111, 0xF, 0xF, false));
}
__device__ __forceinline__ float dpp_shl1(float x) {
    int v = __float_as_int(x);
    return __int_as_float(__builtin_amdgcn_update_dpp(v, v, 0x101, 0xF, 0xF, false));
}

__device__ __forceinline__ v2f pk_add(v2f a, v2f b) {
    v2f d; asm("v_pk_add_f32 %0, %1, %2" : "=v"(d) : "v"(a), "v"(b)); return d;
}
__device__ __forceinline__ v2f pk_fma(v2f a, v2f b, v2f c) {
    v2f d; asm("v_pk_fma_f32 %0, %1, %2, %3" : "=v"(d) : "v"(a), "v"(b), "v"(c)); return d;
}

__global__ __launch_bounds__(256, 4) void jacobi_fused(const float* __restrict__ src,
                                                       const float* __restrict__ layout,
                                                       float* __restrict__ dst) {
    __shared__ float buf[2][LROWS * PITCH];

    const float COF = (float)(0.25 * (0.1 / 1023.0) * (0.1 / 1023.0));

    const int tid = threadIdx.x;
    const int g = tid & 15;                      // col group: data cols 4g..4g+3
    const int c = tid >> 4;                      // row chunk: buffer rows 1+4c..4+4c
    const int gr0 = blockIdx.y * OUT - TSTEPS;
    const int gc0 = blockIdx.x * OUT - TSTEPS;
    const int base = blockIdx.z * NX * NX;
    const int R0 = 1 + 4 * c;
    const int C0 = 4 * g;

    v2f fE[4], fO[4];

    const bool interior = (blockIdx.x >= 1) && (blockIdx.x <= 22) &&
                          (blockIdx.y >= 1) && (blockIdx.y <= 22);

    if (interior) {
        // ---- fast staging: 8 coalesced float2 loads, bit-swapped into E/O LDS layout ----
        const float* sb = src + base + gr0 * NX + gc0;
#pragma unroll
        for (int k = 0; k < 8; ++k) {
            int idx2 = tid + 256 * k;
            int r = idx2 >> 5, q2 = idx2 & 31;
            v2f v = *(const v2f*)(sb + r * NX + 2 * q2);
            int lo = 4 * (q2 >> 1) + (q2 & 1);     // cols (2q2,2q2+1) -> positions (lo, lo+2)
            buf[0][r * PITCH + lo]     = v.x;
            buf[0][r * PITCH + lo + 2] = v.y;
        }
        const float* lb = layout + base + gc0 + C0;
#pragma unroll
        for (int i = 0; i < 4; ++i) {
            v2f a = *(const v2f*)(lb + (gr0 + R0 + i) * NX);
            v2f b = *(const v2f*)(lb + (gr0 + R0 + i) * NX + 2);
            fE[i] = (v2f){COF * a.x, COF * b.x};
            fO[i] = (v2f){COF * a.y, COF * b.y};
        }
    } else {
        // ---- slow staging: reflect-mapped scalar loads, bit-swapped cols ----
#pragma unroll
        for (int k = 0; k < 16; ++k) {
            int idx = tid + 256 * k;
            int r = idx >> 6, q = idx & 63;
            int lo = (q & ~3) | ((q & 1) << 1) | ((q >> 1) & 1);   // swap low 2 bits
            buf[0][r * PITCH + lo] = src[base + reflect_idx(gr0 + r) * NX + reflect_idx(gc0 + q)];
        }
#pragma unroll
        for (int i = 0; i < 4; ++i) {
            int grr = reflect_idx(gr0 + R0 + i);
            float f0 = layout[base + grr * NX + reflect_idx(gc0 + C0)];
            float f1 = layout[base + grr * NX + reflect_idx(gc0 + C0 + 1)];
            float f2 = layout[base + grr * NX + reflect_idx(gc0 + C0 + 2)];
            float f3 = layout[base + grr * NX + reflect_idx(gc0 + C0 + 3)];
            fE[i] = (v2f){COF * f0, COF * f2};
            fO[i] = (v2f){COF * f1, COF * f3};
        }
    }
    __syncthreads();

    // ---- load center 4 rows (already in E/O order in LDS) ----
    v2f E[4], O[4];
#pragma unroll
    for (int i = 0; i < 4; ++i) {
        float4 v = *(const float4*)&buf[0][(R0 + i) * PITCH + C0];
        E[i] = (v2f){v.x, v.y};
        O[i] = (v2f){v.z, v.w};
    }

    const v2f qq = (v2f){0.25f, 0.25f};

    // ---- 10 fused steps; only boundary rows touch LDS ----
#pragma unroll
    for (int s = 0; s < TSTEPS; ++s) {
        if (s > 0) {
            float* bb = buf[s & 1];
            *(float4*)&bb[R0 * PITCH + C0]       = make_float4(E[0].x, E[0].y, O[0].x, O[0].y);
            *(float4*)&bb[(R0 + 3) * PITCH + C0] = make_float4(E[3].x, E[3].y, O[3].x, O[3].y);
            __syncthreads();
        }
        const float* rb = (s == 0) ? buf[0] : buf[s & 1];
        float4 t  = *(const float4*)&rb[(R0 - 1) * PITCH + C0];
        float4 bo = *(const float4*)&rb[(R0 + 4) * PITCH + C0];
        v2f topE = (v2f){t.x, t.y},  topO = (v2f){t.z, t.w};
        v2f botE = (v2f){bo.x, bo.y}, botO = (v2f){bo.z, bo.w};

        v2f nE[4], nO[4];
#pragma unroll
        for (int i = 0; i < 4; ++i) {
            v2f upE = (i == 0) ? topE : E[i - 1], upO = (i == 0) ? topO : O[i - 1];
            v2f dnE = (i == 3) ? botE : E[i + 1], dnO = (i == 3) ? botO : O[i + 1];
            v2f vE = pk_add(upE, dnE);
            v2f vO = pk_add(upO, dnO);
            v2f P; P.x = dpp_shr1(O[i].y); P.y = O[i].x;   // (lf, c1)
            v2f Q; Q.x = E[i].y; Q.y = dpp_shl1(E[i].x);   // (c2, rt)
            v2f hE = pk_add(P, O[i]);                      // (lf+c1, c1+c3)
            v2f hO = pk_add(E[i], Q);                      // (c0+c2, c2+rt)
            nE[i] = pk_fma(pk_add(vE, hE), qq, fE[i]);
            nO[i] = pk_fma(pk_add(vO, hO), qq, fO[i]);
        }
#pragma unroll
        for (int i = 0; i < 4; ++i) { E[i] = nE[i]; O[i] = nO[i]; }
    }

    // ---- store central 44x44 from registers ----
#pragma unroll
    for (int i = 0; i < 4; ++i) {
        int br = R0 + i;
        bool rowok = (br >= TSTEPS) && (br <= HI) && (gr0 + br < NX);
        float v[4] = {E[i].x, O[i].x, E[i].y, O[i].y};     // c0,c1,c2,c3
#pragma unroll
        for (int k = 0; k < 4; ++k) {
            int dcol = C0 + k;
            if (rowok && dcol >= TSTEPS && dcol <= HI && (gc0 + dcol) < NX)
                dst[base + (gr0 + br) * NX + (gc0 + dcol)] = v[k];
        }
    }
}

extern "C" void kernel_launch(void* const* d_in, const int* in_sizes, int n_in,
                              void* d_out, int out_size, void* d_ws, size_t ws_size,
                              hipStream_t stream) {
    const float* layout = (const float*)d_in[0];
    const float* heat   = (const float*)d_in[1];
    float* out = (float*)d_out;
    float* ws  = (float*)d_ws;

    dim3 grid((NX + OUT - 1) / OUT, (NX + OUT - 1) / OUT, BATCH);  // 24 x 24 x 16
    dim3 block(256);

    jacobi_fused<<<grid, block, 0, stream>>>(heat, layout, out);
    jacobi_fused<<<grid, block, 0, stream>>>(out,  layout, ws);
    jacobi_fused<<<grid, block, 0, stream>>>(ws,   layout, out);
    jacobi_fused<<<grid, block, 0, stream>>>(out,  layout, ws);
    jacobi_fused<<<grid, block, 0, stream>>>(ws,   layout, out);
}